// Round 1
// baseline (1015.955 us; speedup 1.0000x reference)
//
#include <hip/hip_runtime.h>
#include <hip/hip_bf16.h>

// ---------------------------------------------------------------------------
// ResidualBlock: GMMConv(x)->BN->ELU->GMMConv->BN  +  GMMConv_sc(x)->BN ; ELU
// N=50000 nodes, E=800000 edges, C=64, K_main=5, K_sc=1. All fp32.
// Strategy: CSR-by-dst built once, per-node wave aggregation (lane=channel),
// fp32 LDS-tiled GEMMs, fused BN epilogues.
// ---------------------------------------------------------------------------

#define EPS_SIGMA 1e-15f
#define BN_EPS    1e-5f

// --- dtype detect: int64 edge_index has all-zero high words -----------------
__global__ void detect_kernel(const void* ei, int* flag) {
  const int* p = (const int*)ei;
  int allzero = 1;
  for (int i = 1; i < 512; i += 2) {
    if (p[i] != 0) { allzero = 0; break; }
  }
  *flag = allzero;  // 1 => int64 layout, 0 => int32 layout
}

__device__ __forceinline__ int load_idx(const void* ei, size_t pos, int is64) {
  if (is64) return (int)((const long long*)ei)[pos];
  return ((const int*)ei)[pos];
}

// --- CSR build ---------------------------------------------------------------
__global__ void hist_kernel(const void* ei, int E, const int* flag, int* cnt) {
  int e = blockIdx.x * blockDim.x + threadIdx.x;
  if (e >= E) return;
  int d = load_idx(ei, (size_t)E + e, *flag);
  atomicAdd(&cnt[d], 1);
}

// single-block exclusive scan over cnt -> row_ptr; zeroes cnt for cursor reuse
__global__ void scan_kernel(int* cnt, int* row_ptr, int n) {
  __shared__ int sdata[256];
  int tid = threadIdx.x;
  int carry = 0;
  for (int base = 0; base < n; base += 256) {
    int i = base + tid;
    int v = (i < n) ? cnt[i] : 0;
    sdata[tid] = v;
    __syncthreads();
    for (int off = 1; off < 256; off <<= 1) {
      int t = (tid >= off) ? sdata[tid - off] : 0;
      __syncthreads();
      sdata[tid] += t;
      __syncthreads();
    }
    int incl = sdata[tid];
    int total = sdata[255];
    if (i < n) { row_ptr[i] = carry + incl - v; cnt[i] = 0; }
    carry += total;
    __syncthreads();
  }
  if (tid == 0) row_ptr[n] = carry;
}

__global__ void scatter_kernel(const void* ei, const float* __restrict__ ea, int E,
                               const int* flag, const int* __restrict__ row_ptr,
                               int* cursor, int* __restrict__ csr_src,
                               float* __restrict__ csr_ea) {
  int e = blockIdx.x * blockDim.x + threadIdx.x;
  if (e >= E) return;
  int is64 = *flag;
  int s = load_idx(ei, (size_t)e, is64);
  int d = load_idx(ei, (size_t)E + e, is64);
  int pos = atomicAdd(&cursor[d], 1);
  int slot = row_ptr[d] + pos;
  csr_src[slot] = s;
  csr_ea[slot] = ea[e];
}

// --- fp32 GEMM: C[M,Ncols] = A[M,64] @ B[64,Ncols] (+bias) ------------------
__global__ __launch_bounds__(256) void gemm64(const float* __restrict__ A,
                                              const float* __restrict__ B,
                                              const float* __restrict__ bias,
                                              float* __restrict__ C, int M, int Ncols) {
  __shared__ float As[64][68];  // [m][k], +4 float pad keeps 16B align, kills conflicts
  __shared__ float Bs[64][64];  // [k][n]
  int tile_m = blockIdx.x * 64;
  int tile_n = blockIdx.y * 64;
  int tid = threadIdx.x;
  const float4* A4 = (const float4*)A;
#pragma unroll
  for (int i = 0; i < 4; ++i) {
    int idx = tid + i * 256;   // float4 slot 0..1023
    int r = idx >> 4;          // 0..63
    int c4 = idx & 15;         // 0..15
    float4 v = make_float4(0.f, 0.f, 0.f, 0.f);
    if (tile_m + r < M) v = A4[(size_t)(tile_m + r) * 16 + c4];
    *(float4*)&As[r][c4 * 4] = v;
    float4 bv = *(const float4*)&B[(size_t)r * Ncols + tile_n + c4 * 4];
    *(float4*)&Bs[r][c4 * 4] = bv;
  }
  __syncthreads();
  int tx = tid & 15, ty = tid >> 4;
  float acc[4][4] = {};
#pragma unroll
  for (int k = 0; k < 64; k += 4) {
    float4 b0 = *(const float4*)&Bs[k + 0][tx * 4];
    float4 b1 = *(const float4*)&Bs[k + 1][tx * 4];
    float4 b2 = *(const float4*)&Bs[k + 2][tx * 4];
    float4 b3 = *(const float4*)&Bs[k + 3][tx * 4];
#pragma unroll
    for (int i = 0; i < 4; ++i) {
      float4 a = *(const float4*)&As[ty * 4 + i][k];
      acc[i][0] = fmaf(a.x, b0.x, acc[i][0]);
      acc[i][1] = fmaf(a.x, b0.y, acc[i][1]);
      acc[i][2] = fmaf(a.x, b0.z, acc[i][2]);
      acc[i][3] = fmaf(a.x, b0.w, acc[i][3]);
      acc[i][0] = fmaf(a.y, b1.x, acc[i][0]);
      acc[i][1] = fmaf(a.y, b1.y, acc[i][1]);
      acc[i][2] = fmaf(a.y, b1.z, acc[i][2]);
      acc[i][3] = fmaf(a.y, b1.w, acc[i][3]);
      acc[i][0] = fmaf(a.z, b2.x, acc[i][0]);
      acc[i][1] = fmaf(a.z, b2.y, acc[i][1]);
      acc[i][2] = fmaf(a.z, b2.z, acc[i][2]);
      acc[i][3] = fmaf(a.z, b2.w, acc[i][3]);
      acc[i][0] = fmaf(a.w, b3.x, acc[i][0]);
      acc[i][1] = fmaf(a.w, b3.y, acc[i][1]);
      acc[i][2] = fmaf(a.w, b3.z, acc[i][2]);
      acc[i][3] = fmaf(a.w, b3.w, acc[i][3]);
    }
  }
#pragma unroll
  for (int i = 0; i < 4; ++i) {
    int r = tile_m + ty * 4 + i;
    if (r < M) {
      int cc = tile_n + tx * 4;
      float4 o;
      o.x = acc[i][0]; o.y = acc[i][1]; o.z = acc[i][2]; o.w = acc[i][3];
      if (bias) {
        o.x += bias[cc + 0]; o.y += bias[cc + 1];
        o.z += bias[cc + 2]; o.w += bias[cc + 3];
      }
      *(float4*)&C[(size_t)r * Ncols + cc] = o;
    }
  }
}

// --- aggregation: wave per node, lane = channel ------------------------------
template <int K>
__global__ __launch_bounds__(256) void agg_kernel(const float* __restrict__ xp,
                                                  const float* __restrict__ xr,
                                                  const int* __restrict__ row_ptr,
                                                  const int* __restrict__ csr_src,
                                                  const float* __restrict__ csr_ea,
                                                  const float* __restrict__ mu,
                                                  const float* __restrict__ sig,
                                                  float* __restrict__ out, int n) {
  int node = blockIdx.x * 4 + (threadIdx.x >> 6);
  int lane = threadIdx.x & 63;
  if (node >= n) return;
  float muk[K], ck[K];
#pragma unroll
  for (int k = 0; k < K; ++k) {
    muk[k] = mu[k];
    float s = sig[k];
    ck[k] = -0.5f / (EPS_SIGMA + s * s);
  }
  int beg = row_ptr[node], end = row_ptr[node + 1];
  float acc = 0.f;
  for (int i = beg; i < end; ++i) {
    int s = csr_src[i];
    float p = csr_ea[i];
    const float* xs = xp + (size_t)s * (K * 64) + lane;
#pragma unroll
    for (int k = 0; k < K; ++k) {
      float d = p - muk[k];
      float w = __expf(ck[k] * d * d);
      acc = fmaf(w, xs[k * 64], acc);
    }
  }
  int degi = end - beg;
  float deg = (float)(degi > 1 ? degi : 1);
  size_t o = (size_t)node * 64 + lane;
  out[o] = acc / deg + xr[o];
}

// --- batchnorm ---------------------------------------------------------------
__global__ void bn_stats(const float* __restrict__ h, int n, float* sums, float* sumsq) {
  int c = threadIdx.x & 63;
  int rg = threadIdx.x >> 6;  // 0..3
  float s = 0.f, s2 = 0.f;
  for (int r = blockIdx.x * 4 + rg; r < n; r += gridDim.x * 4) {
    float v = h[(size_t)r * 64 + c];
    s += v;
    s2 = fmaf(v, v, s2);
  }
  __shared__ float ls[4][64], l2[4][64];
  ls[rg][c] = s;
  l2[rg][c] = s2;
  __syncthreads();
  if (threadIdx.x < 64) {
    float ts = ls[0][c] + ls[1][c] + ls[2][c] + ls[3][c];
    float t2 = l2[0][c] + l2[1][c] + l2[2][c] + l2[3][c];
    atomicAdd(&sums[c], ts);
    atomicAdd(&sumsq[c], t2);
  }
}

__global__ void bn_final(const float* sum, const float* sumsq, const float* gamma,
                         const float* beta, int n, float* scale, float* shift) {
  int c = threadIdx.x;
  float m = sum[c] / (float)n;
  float v = sumsq[c] / (float)n - m * m;
  float r = rsqrtf(v + BN_EPS);
  float s = r * gamma[c];
  scale[c] = s;
  shift[c] = beta[c] - m * s;
}

__global__ void norm_elu(float* h, const float* __restrict__ scale,
                         const float* __restrict__ shift, int total) {
  int i = blockIdx.x * 256 + threadIdx.x;
  if (i >= total) return;
  int c = i & 63;
  float v = h[i] * scale[c] + shift[c];
  h[i] = v > 0.f ? v : expm1f(v);
}

__global__ void final_kernel(const float* __restrict__ h2, const float* __restrict__ sc,
                             const float* __restrict__ s2, const float* __restrict__ t2,
                             const float* __restrict__ ss, const float* __restrict__ ts,
                             float* __restrict__ out, int total) {
  int i = blockIdx.x * 256 + threadIdx.x;
  if (i >= total) return;
  int c = i & 63;
  float v = h2[i] * s2[c] + t2[c] + sc[i] * ss[c] + ts[c];
  out[i] = v > 0.f ? v : expm1f(v);
}

// ---------------------------------------------------------------------------
extern "C" void kernel_launch(void* const* d_in, const int* in_sizes, int n_in,
                              void* d_out, int out_size, void* d_ws, size_t ws_size,
                              hipStream_t stream) {
  const float* x    = (const float*)d_in[0];
  const void*  ei   = d_in[1];
  const float* ea   = (const float*)d_in[2];
  const float* g1   = (const float*)d_in[3];
  const float* mu1  = (const float*)d_in[4];
  const float* sig1 = (const float*)d_in[5];
  const float* root1= (const float*)d_in[6];
  const float* b1   = (const float*)d_in[7];
  const float* gam1 = (const float*)d_in[8];
  const float* bet1 = (const float*)d_in[9];
  const float* g2   = (const float*)d_in[10];
  const float* mu2  = (const float*)d_in[11];
  const float* sig2 = (const float*)d_in[12];
  const float* root2= (const float*)d_in[13];
  const float* b2   = (const float*)d_in[14];
  const float* gam2 = (const float*)d_in[15];
  const float* bet2 = (const float*)d_in[16];
  const float* gs   = (const float*)d_in[17];
  const float* mus  = (const float*)d_in[18];
  const float* sigs = (const float*)d_in[19];
  const float* roots= (const float*)d_in[20];
  const float* bs   = (const float*)d_in[21];
  const float* gams = (const float*)d_in[22];
  const float* bets = (const float*)d_in[23];

  int N = in_sizes[0] / 64;
  int E = in_sizes[1] / 2;

  char* w = (char*)d_ws;
  auto alloc = [&](size_t bytes) {
    char* p = w;
    w += (bytes + 255) & ~(size_t)255;
    return p;
  };
  int*   flag    = (int*)alloc(256);
  int*   cnt     = (int*)alloc((size_t)N * 4);
  int*   row_ptr = (int*)alloc((size_t)(N + 1) * 4);
  int*   csr_src = (int*)alloc((size_t)E * 4);
  float* csr_ea  = (float*)alloc((size_t)E * 4);
  float* xp      = (float*)alloc((size_t)N * 320 * 4);
  float* xr      = (float*)alloc((size_t)N * 64 * 4);
  float* h       = (float*)alloc((size_t)N * 64 * 4);
  float* h2      = (float*)alloc((size_t)N * 64 * 4);
  float* scb     = (float*)alloc((size_t)N * 64 * 4);
  float* stats   = (float*)alloc(12 * 64 * 4);
  // stats: [0]=sum1 [1]=sq1 [2]=sum2 [3]=sq2 [4]=sums [5]=sqs
  //        [6]=scale1 [7]=shift1 [8]=scale2 [9]=shift2 [10]=scales [11]=shifts

  hipMemsetAsync(cnt, 0, (size_t)N * 4, stream);
  hipMemsetAsync(stats, 0, 12 * 64 * 4, stream);

  int eb = (E + 255) / 256;
  detect_kernel<<<1, 1, 0, stream>>>(ei, flag);
  hist_kernel<<<eb, 256, 0, stream>>>(ei, E, flag, cnt);
  scan_kernel<<<1, 256, 0, stream>>>(cnt, row_ptr, N);
  scatter_kernel<<<eb, 256, 0, stream>>>(ei, ea, E, flag, row_ptr, cnt, csr_src, csr_ea);

  int mtiles = (N + 63) / 64;
  int nb_node = (N + 3) / 4;
  int nb_elem = (N * 64 + 255) / 256;

  // ---- layer 1 ----
  gemm64<<<dim3(mtiles, 5), 256, 0, stream>>>(x, g1, nullptr, xp, N, 320);
  gemm64<<<dim3(mtiles, 1), 256, 0, stream>>>(x, root1, b1, xr, N, 64);
  agg_kernel<5><<<nb_node, 256, 0, stream>>>(xp, xr, row_ptr, csr_src, csr_ea, mu1, sig1, h, N);
  bn_stats<<<256, 256, 0, stream>>>(h, N, stats + 0 * 64, stats + 1 * 64);
  bn_final<<<1, 64, 0, stream>>>(stats + 0 * 64, stats + 1 * 64, gam1, bet1, N,
                                 stats + 6 * 64, stats + 7 * 64);
  norm_elu<<<nb_elem, 256, 0, stream>>>(h, stats + 6 * 64, stats + 7 * 64, N * 64);

  // ---- layer 2 ----
  gemm64<<<dim3(mtiles, 5), 256, 0, stream>>>(h, g2, nullptr, xp, N, 320);
  gemm64<<<dim3(mtiles, 1), 256, 0, stream>>>(h, root2, b2, xr, N, 64);
  agg_kernel<5><<<nb_node, 256, 0, stream>>>(xp, xr, row_ptr, csr_src, csr_ea, mu2, sig2, h2, N);
  bn_stats<<<256, 256, 0, stream>>>(h2, N, stats + 2 * 64, stats + 3 * 64);
  bn_final<<<1, 64, 0, stream>>>(stats + 2 * 64, stats + 3 * 64, gam2, bet2, N,
                                 stats + 8 * 64, stats + 9 * 64);

  // ---- shortcut ----
  gemm64<<<dim3(mtiles, 1), 256, 0, stream>>>(x, gs, nullptr, xp, N, 64);
  gemm64<<<dim3(mtiles, 1), 256, 0, stream>>>(x, roots, bs, xr, N, 64);
  agg_kernel<1><<<nb_node, 256, 0, stream>>>(xp, xr, row_ptr, csr_src, csr_ea, mus, sigs, scb, N);
  bn_stats<<<256, 256, 0, stream>>>(scb, N, stats + 4 * 64, stats + 5 * 64);
  bn_final<<<1, 64, 0, stream>>>(stats + 4 * 64, stats + 5 * 64, gams, bets, N,
                                 stats + 10 * 64, stats + 11 * 64);

  // ---- fused BN2 + BNsc + add + ELU ----
  final_kernel<<<nb_elem, 256, 0, stream>>>(h2, scb, stats + 8 * 64, stats + 9 * 64,
                                            stats + 10 * 64, stats + 11 * 64,
                                            (float*)d_out, N * 64);
}

// Round 2
// 485.636 us; speedup vs baseline: 2.0920x; 2.0920x over previous
//
#include <hip/hip_runtime.h>
#include <hip/hip_bf16.h>

// ---------------------------------------------------------------------------
// ResidualBlock: GMMConv(x)->BN->ELU->GMMConv->BN  +  GMMConv_sc(x)->BN ; ELU
// N=50000, E=800000, C=64, K_main=5, K_sc=1. fp32.
// Round 2: fast 3-kernel scan; aggregate RAW features per-gaussian (5x less
// gather traffic), fused layer1+shortcut agg pass; GEMM applies [Gr; root]
// after aggregation (K=320+64 chunked), bias fused.
// ---------------------------------------------------------------------------

#define EPS_SIGMA 1e-15f
#define BN_EPS    1e-5f

// --- dtype detect: int64 edge_index has all-zero high words -----------------
__global__ void detect_kernel(const void* ei, int* flag) {
  const int* p = (const int*)ei;
  int allzero = 1;
  for (int i = 1; i < 512; i += 2) {
    if (p[i] != 0) { allzero = 0; break; }
  }
  *flag = allzero;  // 1 => int64 layout, 0 => int32 layout
}

__device__ __forceinline__ int load_idx(const void* ei, size_t pos, int is64) {
  if (is64) return (int)((const long long*)ei)[pos];
  return ((const int*)ei)[pos];
}

// --- CSR build ---------------------------------------------------------------
__global__ void hist_kernel(const void* ei, int E, const int* flag, int* cnt) {
  int e = blockIdx.x * blockDim.x + threadIdx.x;
  if (e >= E) return;
  int d = load_idx(ei, (size_t)E + e, *flag);
  atomicAdd(&cnt[d], 1);
}

// decoupled scan: blocks of 2048 elems -> partials -> add offsets
__global__ __launch_bounds__(256) void scan1(const int* __restrict__ cnt,
                                             int* __restrict__ row_ptr,
                                             int* __restrict__ partials, int n) {
  int tid = threadIdx.x;
  int base = blockIdx.x * 2048 + tid * 8;
  int v[8], pre[8];
  int run = 0;
#pragma unroll
  for (int j = 0; j < 8; ++j) {
    int idx = base + j;
    v[j] = (idx < n) ? cnt[idx] : 0;
    pre[j] = run;
    run += v[j];
  }
  __shared__ int sd[256];
  sd[tid] = run;
  __syncthreads();
  for (int off = 1; off < 256; off <<= 1) {
    int t = (tid >= off) ? sd[tid - off] : 0;
    __syncthreads();
    sd[tid] += t;
    __syncthreads();
  }
  int excl = sd[tid] - run;
#pragma unroll
  for (int j = 0; j < 8; ++j) {
    int idx = base + j;
    if (idx < n) row_ptr[idx] = excl + pre[j];
  }
  if (tid == 255) partials[blockIdx.x] = sd[255];
}

__global__ void scan2(int* partials, int nb, int* row_ptr, int n) {
  __shared__ int sd[256];
  int tid = threadIdx.x;
  int v = (tid < nb) ? partials[tid] : 0;
  sd[tid] = v;
  __syncthreads();
  for (int off = 1; off < 256; off <<= 1) {
    int t = (tid >= off) ? sd[tid - off] : 0;
    __syncthreads();
    sd[tid] += t;
    __syncthreads();
  }
  if (tid < nb) partials[tid] = sd[tid] - v;   // exclusive
  if (tid == nb - 1) row_ptr[n] = sd[tid];     // total = E
}

__global__ void scan3(int* __restrict__ row_ptr, const int* __restrict__ partials,
                      int* __restrict__ cnt, int n) {
  int i = blockIdx.x * 256 + threadIdx.x;
  if (i < n) {
    row_ptr[i] += partials[i >> 11];
    cnt[i] = 0;  // reset for scatter cursor
  }
}

__global__ void scatter_kernel(const void* ei, const float* __restrict__ ea, int E,
                               const int* flag, const int* __restrict__ row_ptr,
                               int* cursor, int* __restrict__ csr_src,
                               float* __restrict__ csr_ea) {
  int e = blockIdx.x * blockDim.x + threadIdx.x;
  if (e >= E) return;
  int is64 = *flag;
  int s = load_idx(ei, (size_t)e, is64);
  int d = load_idx(ei, (size_t)E + e, is64);
  int pos = atomicAdd(&cursor[d], 1);
  int slot = row_ptr[d] + pos;
  csr_src[slot] = s;
  csr_ea[slot] = ea[e];
}

// --- weight prep: Bout[(K*64+64) x 64] = [rearranged G ; root] ---------------
// Gr[k*64+i][j] = g[i][k*64+j]
__global__ void prep_cat(const float* __restrict__ g, const float* __restrict__ root,
                         float* __restrict__ Bout, int K) {
  int idx = blockIdx.x * 256 + threadIdx.x;
  int total = (K + 1) * 64 * 64;
  if (idx >= total) return;
  int r = idx >> 6, c = idx & 63;
  float v;
  if (r < K * 64) {
    int k = r >> 6, i = r & 63;
    v = g[i * (K * 64) + k * 64 + c];
  } else {
    v = root[(r - K * 64) * 64 + c];
  }
  Bout[idx] = v;
}

// --- aggregation of RAW features, KA+KB gaussian mixtures --------------------
// out[node*ldo + k*64 + lane] = invdeg * sum_e gauss_k(e) * feat[src(e)][lane]
template <int KA, int KB>
__global__ __launch_bounds__(256) void agg_raw(const float* __restrict__ feat,
                                               const int* __restrict__ row_ptr,
                                               const int* __restrict__ csr_src,
                                               const float* __restrict__ csr_ea,
                                               const float* __restrict__ muA,
                                               const float* __restrict__ sigA,
                                               const float* __restrict__ muB,
                                               const float* __restrict__ sigB,
                                               float* __restrict__ out, int n, int ldo) {
  int node = blockIdx.x * 4 + (threadIdx.x >> 6);
  int lane = threadIdx.x & 63;
  if (node >= n) return;
  const int KT = KA + KB;
  float mk[KT], ck[KT];
#pragma unroll
  for (int k = 0; k < KA; ++k) {
    mk[k] = muA[k];
    float s = sigA[k];
    ck[k] = -0.5f / (EPS_SIGMA + s * s);
  }
#pragma unroll
  for (int k = 0; k < KB; ++k) {
    mk[KA + k] = muB[k];
    float s = sigB[k];
    ck[KA + k] = -0.5f / (EPS_SIGMA + s * s);
  }
  int beg = row_ptr[node], end = row_ptr[node + 1];
  float acc[KT];
#pragma unroll
  for (int k = 0; k < KT; ++k) acc[k] = 0.f;
  for (int i = beg; i < end; ++i) {
    int s = csr_src[i];
    float p = csr_ea[i];
    float xv = feat[(size_t)s * 64 + lane];
#pragma unroll
    for (int k = 0; k < KT; ++k) {
      float d = p - mk[k];
      float w = __expf(ck[k] * d * d);
      acc[k] = fmaf(w, xv, acc[k]);
    }
  }
  int degi = end - beg;
  float invdeg = 1.0f / (float)(degi > 1 ? degi : 1);
  size_t o = (size_t)node * ldo + lane;
#pragma unroll
  for (int k = 0; k < KT; ++k) out[o + k * 64] = acc[k] * invdeg;
}

// --- GEMM: C[M,64] = [A1(K1 cols, lda1) | A2(64 cols)] @ B[K1+64,64] + bias --
__global__ __launch_bounds__(256) void gemm_fused(const float* __restrict__ A1, int lda1,
                                                  int K1, const float* __restrict__ A2,
                                                  const float* __restrict__ B,
                                                  const float* __restrict__ bias,
                                                  float* __restrict__ C, int M) {
  __shared__ float As[64][68];
  __shared__ float Bs[64][64];
  int tile_m = blockIdx.x * 64;
  int tid = threadIdx.x;
  int tx = tid & 15, ty = tid >> 4;
  float acc[4][4] = {};
  int nch = K1 >> 6;
  for (int ch = 0; ch <= nch; ++ch) {
    const float* Ap;
    int lda, kb;
    if (ch < nch) { Ap = A1; lda = lda1; kb = ch * 64; }
    else          { Ap = A2; lda = 64;   kb = 0; }
#pragma unroll
    for (int i = 0; i < 4; ++i) {
      int idx = tid + i * 256;
      int r = idx >> 4, c4 = idx & 15;
      float4 v = make_float4(0.f, 0.f, 0.f, 0.f);
      if (tile_m + r < M) v = *(const float4*)&Ap[(size_t)(tile_m + r) * lda + kb + c4 * 4];
      *(float4*)&As[r][c4 * 4] = v;
      *(float4*)&Bs[r][c4 * 4] = *(const float4*)&B[(size_t)(ch * 64 + r) * 64 + c4 * 4];
    }
    __syncthreads();
#pragma unroll
    for (int k = 0; k < 64; k += 4) {
      float4 b0 = *(const float4*)&Bs[k + 0][tx * 4];
      float4 b1 = *(const float4*)&Bs[k + 1][tx * 4];
      float4 b2 = *(const float4*)&Bs[k + 2][tx * 4];
      float4 b3 = *(const float4*)&Bs[k + 3][tx * 4];
#pragma unroll
      for (int i = 0; i < 4; ++i) {
        float4 a = *(const float4*)&As[ty * 4 + i][k];
        acc[i][0] = fmaf(a.x, b0.x, acc[i][0]);
        acc[i][1] = fmaf(a.x, b0.y, acc[i][1]);
        acc[i][2] = fmaf(a.x, b0.z, acc[i][2]);
        acc[i][3] = fmaf(a.x, b0.w, acc[i][3]);
        acc[i][0] = fmaf(a.y, b1.x, acc[i][0]);
        acc[i][1] = fmaf(a.y, b1.y, acc[i][1]);
        acc[i][2] = fmaf(a.y, b1.z, acc[i][2]);
        acc[i][3] = fmaf(a.y, b1.w, acc[i][3]);
        acc[i][0] = fmaf(a.z, b2.x, acc[i][0]);
        acc[i][1] = fmaf(a.z, b2.y, acc[i][1]);
        acc[i][2] = fmaf(a.z, b2.z, acc[i][2]);
        acc[i][3] = fmaf(a.z, b2.w, acc[i][3]);
        acc[i][0] = fmaf(a.w, b3.x, acc[i][0]);
        acc[i][1] = fmaf(a.w, b3.y, acc[i][1]);
        acc[i][2] = fmaf(a.w, b3.z, acc[i][2]);
        acc[i][3] = fmaf(a.w, b3.w, acc[i][3]);
      }
    }
    __syncthreads();
  }
#pragma unroll
  for (int i = 0; i < 4; ++i) {
    int r = tile_m + ty * 4 + i;
    if (r < M) {
      int cc = tx * 4;
      float4 o;
      o.x = acc[i][0] + bias[cc + 0];
      o.y = acc[i][1] + bias[cc + 1];
      o.z = acc[i][2] + bias[cc + 2];
      o.w = acc[i][3] + bias[cc + 3];
      *(float4*)&C[(size_t)r * 64 + cc] = o;
    }
  }
}

// --- batchnorm ---------------------------------------------------------------
__global__ void bn_stats(const float* __restrict__ h, int n, float* sums, float* sumsq) {
  int c = threadIdx.x & 63;
  int rg = threadIdx.x >> 6;
  float s = 0.f, s2 = 0.f;
  for (int r = blockIdx.x * 4 + rg; r < n; r += gridDim.x * 4) {
    float v = h[(size_t)r * 64 + c];
    s += v;
    s2 = fmaf(v, v, s2);
  }
  __shared__ float ls[4][64], l2[4][64];
  ls[rg][c] = s;
  l2[rg][c] = s2;
  __syncthreads();
  if (threadIdx.x < 64) {
    float ts = ls[0][c] + ls[1][c] + ls[2][c] + ls[3][c];
    float t2 = l2[0][c] + l2[1][c] + l2[2][c] + l2[3][c];
    atomicAdd(&sums[c], ts);
    atomicAdd(&sumsq[c], t2);
  }
}

__global__ void bn_final(const float* sum, const float* sumsq, const float* gamma,
                         const float* beta, int n, float* scale, float* shift) {
  int c = threadIdx.x;
  float m = sum[c] / (float)n;
  float v = sumsq[c] / (float)n - m * m;
  float r = rsqrtf(v + BN_EPS);
  float s = r * gamma[c];
  scale[c] = s;
  shift[c] = beta[c] - m * s;
}

__global__ void norm_elu(float* h, const float* __restrict__ scale,
                         const float* __restrict__ shift, int total) {
  int i = blockIdx.x * 256 + threadIdx.x;
  if (i >= total) return;
  int c = i & 63;
  float v = h[i] * scale[c] + shift[c];
  h[i] = v > 0.f ? v : expm1f(v);
}

__global__ void final_kernel(const float* __restrict__ h2, const float* __restrict__ sc,
                             const float* __restrict__ s2, const float* __restrict__ t2,
                             const float* __restrict__ ss, const float* __restrict__ ts,
                             float* __restrict__ out, int total) {
  int i = blockIdx.x * 256 + threadIdx.x;
  if (i >= total) return;
  int c = i & 63;
  float v = h2[i] * s2[c] + t2[c] + sc[i] * ss[c] + ts[c];
  out[i] = v > 0.f ? v : expm1f(v);
}

// ---------------------------------------------------------------------------
extern "C" void kernel_launch(void* const* d_in, const int* in_sizes, int n_in,
                              void* d_out, int out_size, void* d_ws, size_t ws_size,
                              hipStream_t stream) {
  const float* x    = (const float*)d_in[0];
  const void*  ei   = d_in[1];
  const float* ea   = (const float*)d_in[2];
  const float* g1   = (const float*)d_in[3];
  const float* mu1  = (const float*)d_in[4];
  const float* sig1 = (const float*)d_in[5];
  const float* root1= (const float*)d_in[6];
  const float* b1   = (const float*)d_in[7];
  const float* gam1 = (const float*)d_in[8];
  const float* bet1 = (const float*)d_in[9];
  const float* g2   = (const float*)d_in[10];
  const float* mu2  = (const float*)d_in[11];
  const float* sig2 = (const float*)d_in[12];
  const float* root2= (const float*)d_in[13];
  const float* b2   = (const float*)d_in[14];
  const float* gam2 = (const float*)d_in[15];
  const float* bet2 = (const float*)d_in[16];
  const float* gs   = (const float*)d_in[17];
  const float* mus  = (const float*)d_in[18];
  const float* sigs = (const float*)d_in[19];
  const float* roots= (const float*)d_in[20];
  const float* bs   = (const float*)d_in[21];
  const float* gams = (const float*)d_in[22];
  const float* bets = (const float*)d_in[23];

  int N = in_sizes[0] / 64;
  int E = in_sizes[1] / 2;

  char* w = (char*)d_ws;
  auto alloc = [&](size_t bytes) {
    char* p = w;
    w += (bytes + 255) & ~(size_t)255;
    return p;
  };
  int*   flag    = (int*)alloc(256);
  int*   cnt     = (int*)alloc((size_t)N * 4);
  int*   row_ptr = (int*)alloc((size_t)(N + 1) * 4);
  int*   partials= (int*)alloc(256 * 4);
  int*   csr_src = (int*)alloc((size_t)E * 4);
  float* csr_ea  = (float*)alloc((size_t)E * 4);
  float* Abuf    = (float*)alloc((size_t)N * 384 * 4);  // layer1: [agg1(320)|aggsc(64)]; reused layer2: [agg2(320)]
  float* h       = (float*)alloc((size_t)N * 64 * 4);
  float* h2      = (float*)alloc((size_t)N * 64 * 4);
  float* scb     = (float*)alloc((size_t)N * 64 * 4);
  float* B1cat   = (float*)alloc(384 * 64 * 4);
  float* B2cat   = (float*)alloc(384 * 64 * 4);
  float* Bsc     = (float*)alloc(128 * 64 * 4);
  float* stats   = (float*)alloc(12 * 64 * 4);

  hipMemsetAsync(cnt, 0, (size_t)N * 4, stream);
  hipMemsetAsync(stats, 0, 12 * 64 * 4, stream);

  int eb = (E + 255) / 256;
  int nb1 = (N + 2047) / 2048;

  // weight prep (independent, launch first)
  prep_cat<<<(6 * 4096 + 255) / 256, 256, 0, stream>>>(g1, root1, B1cat, 5);
  prep_cat<<<(6 * 4096 + 255) / 256, 256, 0, stream>>>(g2, root2, B2cat, 5);
  prep_cat<<<(2 * 4096 + 255) / 256, 256, 0, stream>>>(gs, roots, Bsc, 1);

  // CSR build
  detect_kernel<<<1, 1, 0, stream>>>(ei, flag);
  hist_kernel<<<eb, 256, 0, stream>>>(ei, E, flag, cnt);
  scan1<<<nb1, 256, 0, stream>>>(cnt, row_ptr, partials, N);
  scan2<<<1, 256, 0, stream>>>(partials, nb1, row_ptr, N);
  scan3<<<(N + 255) / 256, 256, 0, stream>>>(row_ptr, partials, cnt, N);
  scatter_kernel<<<eb, 256, 0, stream>>>(ei, ea, E, flag, row_ptr, cnt, csr_src, csr_ea);

  int mtiles = (N + 63) / 64;
  int nb_node = (N + 3) / 4;
  int nb_elem = (N * 64 + 255) / 256;

  // ---- fused layer1 + shortcut aggregation over raw x ----
  agg_raw<5, 1><<<nb_node, 256, 0, stream>>>(x, row_ptr, csr_src, csr_ea,
                                             mu1, sig1, mus, sigs, Abuf, N, 384);
  // h = [agg1 | x] @ [G1r; root1] + b1
  gemm_fused<<<mtiles, 256, 0, stream>>>(Abuf, 384, 320, x, B1cat, b1, h, N);
  // scb = [aggsc | x] @ [gs; roots] + bs
  gemm_fused<<<mtiles, 256, 0, stream>>>(Abuf + 320, 384, 64, x, Bsc, bs, scb, N);

  // BN1 + ELU on h
  bn_stats<<<256, 256, 0, stream>>>(h, N, stats + 0 * 64, stats + 1 * 64);
  bn_final<<<1, 64, 0, stream>>>(stats + 0 * 64, stats + 1 * 64, gam1, bet1, N,
                                 stats + 6 * 64, stats + 7 * 64);
  norm_elu<<<nb_elem, 256, 0, stream>>>(h, stats + 6 * 64, stats + 7 * 64, N * 64);

  // ---- layer2 aggregation over h (Abuf reused, ldo=320) ----
  agg_raw<5, 0><<<nb_node, 256, 0, stream>>>(h, row_ptr, csr_src, csr_ea,
                                             mu2, sig2, nullptr, nullptr, Abuf, N, 320);
  gemm_fused<<<mtiles, 256, 0, stream>>>(Abuf, 320, 320, h, B2cat, b2, h2, N);

  // BN2 / BNsc stats
  bn_stats<<<256, 256, 0, stream>>>(h2, N, stats + 2 * 64, stats + 3 * 64);
  bn_final<<<1, 64, 0, stream>>>(stats + 2 * 64, stats + 3 * 64, gam2, bet2, N,
                                 stats + 8 * 64, stats + 9 * 64);
  bn_stats<<<256, 256, 0, stream>>>(scb, N, stats + 4 * 64, stats + 5 * 64);
  bn_final<<<1, 64, 0, stream>>>(stats + 4 * 64, stats + 5 * 64, gams, bets, N,
                                 stats + 10 * 64, stats + 11 * 64);

  // ---- fused BN2 + BNsc + add + ELU ----
  final_kernel<<<nb_elem, 256, 0, stream>>>(h2, scb, stats + 8 * 64, stats + 9 * 64,
                                            stats + 10 * 64, stats + 11 * 64,
                                            (float*)d_out, N * 64);
}